// Round 5
// baseline (638.469 us; speedup 1.0000x reference)
//
#include <hip/hip_runtime.h>
#include <hip/hip_bf16.h>
#include <math.h>

// Problem constants
constexpr int B_ = 8;
constexpr int L_ = 2048;
constexpr int S_ = 1000;
constexpr int D_ = 1024;
constexpr int H_ = 8;
constexpr int E_ = 128;     // D/H
constexpr int TOPK_ = 10;
// (1/sqrt(E)) * log2(e): scores in log2 domain so p = exp2(sc)
constexpr float SCALE_LOG2E_ = 0.12751744f;

typedef __attribute__((ext_vector_type(8))) short short8;   // 8 x bf16 (4 VGPRs)
typedef __attribute__((ext_vector_type(4))) float f32x4;

__device__ inline unsigned short f2bf(float x) {            // RTN-even f32->bf16
    unsigned u = __float_as_uint(x);
    unsigned r = (u + 0x7fffu + ((u >> 16) & 1u)) >> 16;
    return (unsigned short)r;
}
__device__ inline float bf2f(unsigned short s) {
    return __uint_as_float(((unsigned)s) << 16);
}

// ---------------------------------------------------------------------------
// Generic f32 GEMM + bias (used only for the tiny 80x1024 output GEMM)
// ---------------------------------------------------------------------------
__global__ __launch_bounds__(256) void gemm_bias_kernel(
    const float* __restrict__ A, const float* __restrict__ Bm,
    const float* __restrict__ bias, float* __restrict__ C,
    int M, int N, int Kd)
{
    __shared__ float As[16][65];
    __shared__ float Bs[16][68];

    const int t  = threadIdx.x;
    const int tx = t & 15;
    const int ty = t >> 4;
    const int m0 = blockIdx.y * 64;
    const int n0 = blockIdx.x * 64;

    float acc[4][4];
#pragma unroll
    for (int i = 0; i < 4; ++i)
#pragma unroll
        for (int j = 0; j < 4; ++j) acc[i][j] = 0.f;

    for (int k0 = 0; k0 < Kd; k0 += 16) {
        {
            const int row = t >> 2;
            const int c4  = (t & 3) * 4;
            float4 v = {0.f, 0.f, 0.f, 0.f};
            if (m0 + row < M)
                v = *(const float4*)&A[(size_t)(m0 + row) * Kd + k0 + c4];
            As[c4 + 0][row] = v.x;
            As[c4 + 1][row] = v.y;
            As[c4 + 2][row] = v.z;
            As[c4 + 3][row] = v.w;
        }
        {
            const int row = t >> 4;
            const int c4  = (t & 15) * 4;
            float4 v = *(const float4*)&Bm[(size_t)(k0 + row) * N + n0 + c4];
            *(float4*)&Bs[row][c4] = v;
        }
        __syncthreads();
#pragma unroll
        for (int k = 0; k < 16; ++k) {
            float a[4], b[4];
#pragma unroll
            for (int i = 0; i < 4; ++i) a[i] = As[k][ty * 4 + i];
            float4 bv = *(const float4*)&Bs[k][tx * 4];
            b[0] = bv.x; b[1] = bv.y; b[2] = bv.z; b[3] = bv.w;
#pragma unroll
            for (int i = 0; i < 4; ++i)
#pragma unroll
                for (int j = 0; j < 4; ++j) acc[i][j] += a[i] * b[j];
        }
        __syncthreads();
    }

#pragma unroll
    for (int i = 0; i < 4; ++i) {
        const int row = m0 + ty * 4 + i;
        if (row < M) {
#pragma unroll
            for (int j = 0; j < 4; ++j) {
                const int col = n0 + tx * 4 + j;
                C[(size_t)row * N + col] = acc[i][j] + bias[col];
            }
        }
    }
}

// ---------------------------------------------------------------------------
// WT split (transpose + hi/lo): WTh/WTl[n][k] = split(W[k][n]). (r2-proven)
// ---------------------------------------------------------------------------
__global__ __launch_bounds__(256) void splitWT_kernel(
    const float* __restrict__ W,
    unsigned short* __restrict__ WTh, unsigned short* __restrict__ WTl)
{
    __shared__ __attribute__((aligned(16))) float tile[64][68];
    const int t  = threadIdx.x;
    const int k0 = blockIdx.y * 64, n0 = blockIdx.x * 64;
#pragma unroll
    for (int it = 0; it < 4; ++it) {
        int id = it * 256 + t;
        int r = id >> 4, c = id & 15;
        *(float4*)&tile[r][c * 4] = *(const float4*)&W[(size_t)(k0 + r) * D_ + n0 + c * 4];
    }
    __syncthreads();
#pragma unroll
    for (int it = 0; it < 4; ++it) {
        int id = it * 256 + t;
        int n = id >> 4, c = id & 15;
        unsigned short hs[4], ls[4];
#pragma unroll
        for (int i = 0; i < 4; ++i) {
            float x = tile[c * 4 + i][n];
            hs[i] = f2bf(x);
            ls[i] = f2bf(x - bf2f(hs[i]));
        }
        size_t o = (size_t)(n0 + n) * D_ + k0 + c * 4;
        uint2 uh; uh.x = (unsigned)hs[0] | ((unsigned)hs[1] << 16);
                  uh.y = (unsigned)hs[2] | ((unsigned)hs[3] << 16);
        uint2 ul; ul.x = (unsigned)ls[0] | ((unsigned)ls[1] << 16);
                  ul.y = (unsigned)ls[2] | ((unsigned)ls[3] << 16);
        *(uint2*)&WTh[o] = uh;
        *(uint2*)&WTl[o] = ul;
    }
}

// ---------------------------------------------------------------------------
// src split: Sh/Sl[1024(pad)][1024] bf16 hi/lo; rows >= 1000 zeroed.
// ---------------------------------------------------------------------------
__global__ __launch_bounds__(256) void split_src_kernel(
    const float* __restrict__ src,
    unsigned short* __restrict__ Sh, unsigned short* __restrict__ Sl)
{
    int idx  = blockIdx.x * 256 + threadIdx.x;
    int base = idx * 4;
    int row  = base >> 10;
    float4 v = {0.f, 0.f, 0.f, 0.f};
    if (row < S_) v = *(const float4*)&src[base];
    float xs[4] = {v.x, v.y, v.z, v.w};
    unsigned short hs[4], ls[4];
#pragma unroll
    for (int i = 0; i < 4; ++i) {
        hs[i] = f2bf(xs[i]);
        ls[i] = f2bf(xs[i] - bf2f(hs[i]));
    }
    uint2 uh; uh.x = (unsigned)hs[0] | ((unsigned)hs[1] << 16);
              uh.y = (unsigned)hs[2] | ((unsigned)hs[3] << 16);
    uint2 ul; ul.x = (unsigned)ls[0] | ((unsigned)ls[1] << 16);
              ul.y = (unsigned)ls[2] | ((unsigned)ls[3] << 16);
    *(uint2*)&Sh[base] = uh;
    *(uint2*)&Sl[base] = ul;
}

// ---------------------------------------------------------------------------
// K projection via 3-term split-bf16 MFMA (r3 structure, re-audited).
// Writes Kbuf (f32, path to output) AND Kh/Kl (bf16 hi/lo, pad rows zeroed).
// Tile 128x128, BK=64, 4 waves; grid 8 mb x 8 nb = 64 blocks.
// ---------------------------------------------------------------------------
__global__ __launch_bounds__(256, 2) void kproj_kernel(
    const unsigned short* __restrict__ Sh, const unsigned short* __restrict__ Sl,
    const unsigned short* __restrict__ WkTh, const unsigned short* __restrict__ WkTl,
    const float* __restrict__ bk,
    float* __restrict__ Kbuf,
    unsigned short* __restrict__ Kh, unsigned short* __restrict__ Kl)
{
    __shared__ __attribute__((aligned(16))) unsigned short Ah[128 * 64];
    __shared__ __attribute__((aligned(16))) unsigned short Al[128 * 64];
    __shared__ __attribute__((aligned(16))) unsigned short Bh[128 * 64];
    __shared__ __attribute__((aligned(16))) unsigned short Bl[128 * 64];

    const int t    = threadIdx.x;
    const int lane = t & 63, w = t >> 6;
    const int mb   = blockIdx.x >> 3;
    const int n0   = (blockIdx.x & 7) * 128;

    f32x4 acc[2][8];
#pragma unroll
    for (int m = 0; m < 2; ++m)
#pragma unroll
        for (int n = 0; n < 8; ++n) acc[m][n] = (f32x4){0.f, 0.f, 0.f, 0.f};

    for (int k0 = 0; k0 < D_; k0 += 64) {
        __syncthreads();
#pragma unroll
        for (int it = 0; it < 4; ++it) {
            int id = it * 256 + t;
            int r = id >> 3, c = id & 7;
            int lofs = r * 64 + ((c ^ (r & 7)) << 3);
            size_t ga = (size_t)(mb * 128 + r) * D_ + k0 + c * 8;
            *(uint4*)&Ah[lofs] = *(const uint4*)&Sh[ga];
            *(uint4*)&Al[lofs] = *(const uint4*)&Sl[ga];
            size_t gb = (size_t)(n0 + r) * D_ + k0 + c * 8;
            *(uint4*)&Bh[lofs] = *(const uint4*)&WkTh[gb];
            *(uint4*)&Bl[lofs] = *(const uint4*)&WkTl[gb];
        }
        __syncthreads();

#pragma unroll
        for (int ki = 0; ki < 2; ++ki) {
            short8 ah[2], al[2];
#pragma unroll
            for (int m = 0; m < 2; ++m) {
                int r = w * 32 + m * 16 + (lane & 15);
                int slot = ki * 4 + (lane >> 4);
                int lofs = r * 64 + ((slot ^ (r & 7)) << 3);
                ah[m] = *(short8*)&Ah[lofs];
                al[m] = *(short8*)&Al[lofs];
            }
#pragma unroll
            for (int n = 0; n < 8; ++n) {
                int nn = n * 16 + (lane & 15);
                int slot = ki * 4 + (lane >> 4);
                int lofs = nn * 64 + ((slot ^ (nn & 7)) << 3);
                short8 bh = *(short8*)&Bh[lofs];
                short8 bl = *(short8*)&Bl[lofs];
#pragma unroll
                for (int m = 0; m < 2; ++m) {
                    acc[m][n] = __builtin_amdgcn_mfma_f32_16x16x32_bf16(ah[m], bh, acc[m][n], 0, 0, 0);
                    acc[m][n] = __builtin_amdgcn_mfma_f32_16x16x32_bf16(ah[m], bl, acc[m][n], 0, 0, 0);
                    acc[m][n] = __builtin_amdgcn_mfma_f32_16x16x32_bf16(al[m], bh, acc[m][n], 0, 0, 0);
                }
            }
        }
    }

#pragma unroll
    for (int n = 0; n < 8; ++n) {
        int col = n0 + n * 16 + (lane & 15);
        float bkv = bk[col];
#pragma unroll
        for (int m = 0; m < 2; ++m) {
            int rbase = mb * 128 + w * 32 + m * 16 + ((lane >> 4) << 2);
#pragma unroll
            for (int r = 0; r < 4; ++r) {
                int row = rbase + r;
                unsigned short hh = 0, ll = 0;
                if (row < S_) {
                    float kv = acc[m][n][r] + bkv;
                    Kbuf[(size_t)row * D_ + col] = kv;
                    hh = f2bf(kv);
                    ll = f2bf(kv - bf2f(hh));
                }
                Kh[(size_t)row * D_ + col] = hh;
                Kl[(size_t)row * D_ + col] = ll;
            }
        }
    }
}

// ---------------------------------------------------------------------------
// Q projection, 3-term split, T14-pipelined: global loads for tile k+1 issued
// before the compute of tile k (single LDS buffer; write-early / load-late).
// Output: planar q hi/lo bf16 with SCALE*log2(e) baked in.
// ---------------------------------------------------------------------------
__global__ __launch_bounds__(256, 2) void qproj_kernel(
    const float* __restrict__ tgt,   // pre-offset to chunk start
    const unsigned short* __restrict__ WqTh, const unsigned short* __restrict__ WqTl,
    const float* __restrict__ bq,
    unsigned short* __restrict__ qhb, unsigned short* __restrict__ qlb)
{
    __shared__ __attribute__((aligned(16))) unsigned short Ah[128 * 64];
    __shared__ __attribute__((aligned(16))) unsigned short Al[128 * 64];
    __shared__ __attribute__((aligned(16))) unsigned short Bh[128 * 64];
    __shared__ __attribute__((aligned(16))) unsigned short Bl[128 * 64];

    const int t    = threadIdx.x;
    const int lane = t & 63, w = t >> 6;
    const int mb   = blockIdx.x >> 3;
    const int n0   = (blockIdx.x & 7) * 128;
    const int r0   = t >> 3;        // staging: r = it*32 + r0, c = t&7
    const int c0   = t & 7;

    f32x4 acc[2][8];
#pragma unroll
    for (int m = 0; m < 2; ++m)
#pragma unroll
        for (int n = 0; n < 8; ++n) acc[m][n] = (f32x4){0.f, 0.f, 0.f, 0.f};

    float4 sa0[4], sa1[4];          // staged A (f32, split at write time)
    uint4  sbh[4], sbl[4];          // staged B hi/lo

#define QP_LOAD(K0)                                                         \
    do {                                                                    \
        _Pragma("unroll")                                                   \
        for (int it = 0; it < 4; ++it) {                                    \
            int r = it * 32 + r0;                                           \
            const float* ga = &tgt[(size_t)(mb * 128 + r) * D_ + (K0) + c0 * 8]; \
            sa0[it] = *(const float4*)ga;                                   \
            sa1[it] = *(const float4*)(ga + 4);                             \
            size_t gb = (size_t)(n0 + r) * D_ + (K0) + c0 * 8;              \
            sbh[it] = *(const uint4*)&WqTh[gb];                             \
            sbl[it] = *(const uint4*)&WqTl[gb];                             \
        }                                                                   \
    } while (0)

    QP_LOAD(0);

    for (int ks = 0; ks < 16; ++ks) {
        __syncthreads();            // prior compute done reading LDS
        // write tile ks (A split hi/lo here)
#pragma unroll
        for (int it = 0; it < 4; ++it) {
            int r = it * 32 + r0;
            int lofs = r * 64 + ((c0 ^ (r & 7)) << 3);
            float xs[8] = {sa0[it].x, sa0[it].y, sa0[it].z, sa0[it].w,
                           sa1[it].x, sa1[it].y, sa1[it].z, sa1[it].w};
            unsigned short hs[8], ls[8];
#pragma unroll
            for (int j = 0; j < 8; ++j) {
                hs[j] = f2bf(xs[j]);
                ls[j] = f2bf(xs[j] - bf2f(hs[j]));
            }
            uint4 uh, ul;
            uh.x = (unsigned)hs[0] | ((unsigned)hs[1] << 16);
            uh.y = (unsigned)hs[2] | ((unsigned)hs[3] << 16);
            uh.z = (unsigned)hs[4] | ((unsigned)hs[5] << 16);
            uh.w = (unsigned)hs[6] | ((unsigned)hs[7] << 16);
            ul.x = (unsigned)ls[0] | ((unsigned)ls[1] << 16);
            ul.y = (unsigned)ls[2] | ((unsigned)ls[3] << 16);
            ul.z = (unsigned)ls[4] | ((unsigned)ls[5] << 16);
            ul.w = (unsigned)ls[6] | ((unsigned)ls[7] << 16);
            *(uint4*)&Ah[lofs] = uh;
            *(uint4*)&Al[lofs] = ul;
            *(uint4*)&Bh[lofs] = sbh[it];
            *(uint4*)&Bl[lofs] = sbl[it];
        }
        __syncthreads();
        if (ks < 15) QP_LOAD((ks + 1) * 64);   // overlap with compute below

#pragma unroll
        for (int ki = 0; ki < 2; ++ki) {
            short8 ah[2], al[2];
#pragma unroll
            for (int m = 0; m < 2; ++m) {
                int r = w * 32 + m * 16 + (lane & 15);
                int slot = ki * 4 + (lane >> 4);
                int lofs = r * 64 + ((slot ^ (r & 7)) << 3);
                ah[m] = *(short8*)&Ah[lofs];
                al[m] = *(short8*)&Al[lofs];
            }
#pragma unroll
            for (int n = 0; n < 8; ++n) {
                int nn = n * 16 + (lane & 15);
                int slot = ki * 4 + (lane >> 4);
                int lofs = nn * 64 + ((slot ^ (nn & 7)) << 3);
                short8 bh = *(short8*)&Bh[lofs];
                short8 bl = *(short8*)&Bl[lofs];
#pragma unroll
                for (int m = 0; m < 2; ++m) {
                    acc[m][n] = __builtin_amdgcn_mfma_f32_16x16x32_bf16(ah[m], bh, acc[m][n], 0, 0, 0);
                    acc[m][n] = __builtin_amdgcn_mfma_f32_16x16x32_bf16(ah[m], bl, acc[m][n], 0, 0, 0);
                    acc[m][n] = __builtin_amdgcn_mfma_f32_16x16x32_bf16(al[m], bh, acc[m][n], 0, 0, 0);
                }
            }
        }
    }
#undef QP_LOAD

#pragma unroll
    for (int n = 0; n < 8; ++n) {
        int col = n0 + n * 16 + (lane & 15);
        float bqv = bq[col];
#pragma unroll
        for (int m = 0; m < 2; ++m) {
            int rbase = mb * 128 + w * 32 + m * 16 + ((lane >> 4) << 2);
#pragma unroll
            for (int r = 0; r < 4; ++r) {
                float q = (acc[m][n][r] + bqv) * SCALE_LOG2E_;
                unsigned short hh = f2bf(q);
                qhb[(size_t)(rbase + r) * D_ + col] = hh;
                qlb[(size_t)(rbase + r) * D_ + col] = f2bf(q - bf2f(hh));
            }
        }
    }
}

// ---------------------------------------------------------------------------
// Scores, 2-pass, 3-term split (r4-proven numerics), now double-buffered:
// flat 32-step loop (2 passes x 16 K-tiles); per step: issue loads for tile
// u+1 -> regs, ds_read+MFMA on buf[u&1], ds_write buf[u&1^1], ONE barrier.
// 128 q-rows/block, 4 waves, 32 rows/wave (2 row-groups).
// ---------------------------------------------------------------------------
__global__ __launch_bounds__(256, 2) void scores2p_kernel(
    const unsigned short* __restrict__ qhb, const unsigned short* __restrict__ qlb,
    const unsigned short* __restrict__ Kh, const unsigned short* __restrict__ Kl,
    float* __restrict__ tmps, int b0)
{
    __shared__ __attribute__((aligned(16))) unsigned short SH[2][64 * 128];
    __shared__ __attribute__((aligned(16))) unsigned short SL[2][64 * 128];
    __shared__ float tmps_l[1024];

    const int t    = threadIdx.x;
    const int lane = t & 63, w = t >> 6;
    const int blk  = blockIdx.x;
    const int bb   = blk >> 7;
    const int h    = (blk >> 4) & 7;
    const int lt   = blk & 15;
    const int qrow0 = bb * L_ + lt * 128;        // chunk-local
    const int bh_i  = (b0 + bb) * H_ + h;
    const int kr0   = t >> 4;       // staging: r = it*16 + kr0, c = t&15
    const int kc0   = t & 15;

    for (int i = t; i < 1024; i += 256) tmps_l[i] = 0.f;

    uint4 rh[4], rl[4];             // staged K tile (hi/lo)

#define SC_LOAD(ST)                                                         \
    do {                                                                    \
        _Pragma("unroll")                                                   \
        for (int it = 0; it < 4; ++it) {                                    \
            int r = it * 16 + kr0;                                          \
            size_t g = (size_t)((ST) * 64 + r) * D_ + h * E_ + kc0 * 8;     \
            rh[it] = *(const uint4*)&Kh[g];                                 \
            rl[it] = *(const uint4*)&Kl[g];                                 \
        }                                                                   \
    } while (0)

#define SC_WRITE(BUF)                                                       \
    do {                                                                    \
        _Pragma("unroll")                                                   \
        for (int it = 0; it < 4; ++it) {                                    \
            int r = it * 16 + kr0;                                          \
            int lofs = r * 128 + ((kc0 ^ (r & 15)) << 3);                   \
            *(uint4*)&SH[(BUF)][lofs] = rh[it];                             \
            *(uint4*)&SL[(BUF)][lofs] = rl[it];                             \
        }                                                                   \
    } while (0)

    SC_LOAD(0);                      // K tile 0 in flight during Q staging

    // ---- stage Q (128 rows x 128 cols, hi/lo) via SH[0]/SL[0]; hoist frags
    short8 qh[2][4], ql[2][4];
#pragma unroll
    for (int hf = 0; hf < 2; ++hf) {
        __syncthreads();
#pragma unroll
        for (int it = 0; it < 4; ++it) {
            int r = it * 16 + kr0;
            size_t g = (size_t)(qrow0 + hf * 64 + r) * D_ + h * E_ + kc0 * 8;
            int lofs = r * 128 + ((kc0 ^ (r & 15)) << 3);
            *(uint4*)&SH[0][lofs] = *(const uint4*)&qhb[g];
            *(uint4*)&SL[0][lofs] = *(const uint4*)&qlb[g];
        }
        __syncthreads();
        if ((w >> 1) == hf) {
#pragma unroll
            for (int rg = 0; rg < 2; ++rg)
#pragma unroll
                for (int ki = 0; ki < 4; ++ki) {
                    int rq = (w & 1) * 32 + rg * 16 + (lane & 15);
                    int slot = ki * 4 + (lane >> 4);
                    int lofs = rq * 128 + ((slot ^ (rq & 15)) << 3);
                    qh[rg][ki] = *(short8*)&SH[0][lofs];
                    ql[rg][ki] = *(short8*)&SL[0][lofs];
                }
        }
    }
    __syncthreads();                 // all hoists done; SH[0] reusable
    SC_WRITE(0);                     // K tile 0 -> buf 0
    __syncthreads();

    float zacc[2][4];
#pragma unroll
    for (int rg = 0; rg < 2; ++rg)
#pragma unroll
        for (int r = 0; r < 4; ++r) zacc[rg][r] = 0.f;
    float invZ[2][4];

#pragma unroll 2
    for (int u = 0; u < 32; ++u) {
        const int cur = u & 1;
        const int st  = u & 15;
        if (u < 31) SC_LOAD((u + 1) & 15);   // next tile -> regs (in flight)

        f32x4 acc[2][4];
#pragma unroll
        for (int rg = 0; rg < 2; ++rg)
#pragma unroll
            for (int nf = 0; nf < 4; ++nf) acc[rg][nf] = (f32x4){0.f, 0.f, 0.f, 0.f};

#pragma unroll
        for (int ki = 0; ki < 4; ++ki)
#pragma unroll
            for (int nf = 0; nf < 4; ++nf) {
                int sr = nf * 16 + (lane & 15);
                int slot = ki * 4 + (lane >> 4);
                int lofs = sr * 128 + ((slot ^ (sr & 15)) << 3);
                short8 bh = *(short8*)&SH[cur][lofs];
                short8 bl = *(short8*)&SL[cur][lofs];
#pragma unroll
                for (int rg = 0; rg < 2; ++rg) {
                    acc[rg][nf] = __builtin_amdgcn_mfma_f32_16x16x32_bf16(qh[rg][ki], bh, acc[rg][nf], 0, 0, 0);
                    acc[rg][nf] = __builtin_amdgcn_mfma_f32_16x16x32_bf16(qh[rg][ki], bl, acc[rg][nf], 0, 0, 0);
                    acc[rg][nf] = __builtin_amdgcn_mfma_f32_16x16x32_bf16(ql[rg][ki], bh, acc[rg][nf], 0, 0, 0);
                }
            }

        if (u < 16) {                 // pass 0: accumulate Z
#pragma unroll
            for (int nf = 0; nf < 4; ++nf) {
                int s = st * 64 + nf * 16 + (lane & 15);
                if (s < S_) {
#pragma unroll
                    for (int rg = 0; rg < 2; ++rg)
#pragma unroll
                        for (int r = 0; r < 4; ++r)
                            zacc[rg][r] += exp2f(acc[rg][nf][r]);
                }
            }
            if (u == 15) {
#pragma unroll
                for (int rg = 0; rg < 2; ++rg)
#pragma unroll
                    for (int r = 0; r < 4; ++r) {
                        float z = zacc[rg][r];
                        z += __shfl_xor(z, 1);
                        z += __shfl_xor(z, 2);
                        z += __shfl_xor(z, 4);
                        z += __shfl_xor(z, 8);
                        invZ[rg][r] = 1.f / z;
                    }
            }
        } else {                      // pass 1: p * invZ -> tmps_l
#pragma unroll
            for (int nf = 0; nf < 4; ++nf) {
                int s = st * 64 + nf * 16 + (lane & 15);
                if (s < S_) {
                    float val = 0.f;
#pragma unroll
                    for (int rg = 0; rg < 2; ++rg)
#pragma unroll
                        for (int r = 0; r < 4; ++r)
                            val += exp2f(acc[rg][nf][r]) * invZ[rg][r];
                    atomicAdd(&tmps_l[s], val);
                }
            }
        }

        if (u < 31) SC_WRITE(cur ^ 1);   // tile u+1 -> other buffer
        __syncthreads();
    }
#undef SC_LOAD
#undef SC_WRITE

    for (int i = t; i < S_; i += 256)
        atomicAdd(&tmps[(size_t)bh_i * S_ + i], tmps_l[i]);
}

// ---------------------------------------------------------------------------
// Top-k (k=10) per (b,h); ties -> smaller index (matches jax.lax.top_k).
// ---------------------------------------------------------------------------
__global__ __launch_bounds__(256) void topk_kernel(
    const float* __restrict__ tmps, int* __restrict__ idxs)
{
    const int bh = blockIdx.x;
    const int t  = threadIdx.x;
    __shared__ float v[S_];
    __shared__ float rv[256];
    __shared__ int   ri[256];

    for (int i = t; i < S_; i += 256) v[i] = tmps[(size_t)bh * S_ + i];
    __syncthreads();

    for (int it = 0; it < TOPK_; ++it) {
        float best = -1e38f;
        int bi = 0x7fffffff;
        for (int s = t; s < S_; s += 256) {
            const float x = v[s];
            if (x > best) { best = x; bi = s; }
        }
        rv[t] = best; ri[t] = bi;
        __syncthreads();
        for (int k = 128; k > 0; k >>= 1) {
            if (t < k) {
                const float x = rv[t + k];
                const int  xi = ri[t + k];
                if (x > rv[t] || (x == rv[t] && xi < ri[t])) { rv[t] = x; ri[t] = xi; }
            }
            __syncthreads();
        }
        if (t == 0) {
            idxs[bh * TOPK_ + it] = ri[0];
            v[ri[0]] = -1e38f;
        }
        __syncthreads();
    }
}

// ---------------------------------------------------------------------------
// Gather selected K rows into tok[b][topk][D]
// ---------------------------------------------------------------------------
__global__ __launch_bounds__(256) void gather_kernel(
    const float* __restrict__ K, const int* __restrict__ idxs,
    float* __restrict__ tok)
{
    const int o = blockIdx.x * 256 + threadIdx.x;
    if (o >= B_ * TOPK_ * D_) return;
    const int d  = o & (D_ - 1);
    const int tt = (o >> 10) % TOPK_;
    const int b  = o / (D_ * TOPK_);
    const int h  = d >> 7;
    const int s  = idxs[(b * H_ + h) * TOPK_ + tt];
    tok[o] = K[(size_t)s * D_ + d];
}

// ---------------------------------------------------------------------------
extern "C" void kernel_launch(void* const* d_in, const int* in_sizes, int n_in,
                              void* d_out, int out_size, void* d_ws, size_t ws_size,
                              hipStream_t stream)
{
    const float* tgt = (const float*)d_in[0];
    const float* src = (const float*)d_in[1];
    const float* Wq  = (const float*)d_in[2];
    const float* bq  = (const float*)d_in[3];
    const float* Wk  = (const float*)d_in[4];
    const float* bk  = (const float*)d_in[5];
    const float* Wo  = (const float*)d_in[6];
    const float* bo  = (const float*)d_in[7];
    float* out = (float*)d_out;

    // workspace layout (bytes, all 256-aligned)
    char* ws = (char*)d_ws;
    size_t off = 0;
    float*          Kbuf = (float*)(ws + off);          off += (size_t)S_ * D_ * 4;
    float*          tmps = (float*)(ws + off);          off += (size_t)B_ * H_ * S_ * 4;
    int*            idxs = (int*)(ws + off);            off += (size_t)B_ * H_ * TOPK_ * 4;
    off = (off + 255) & ~(size_t)255;
    float*          tok  = (float*)(ws + off);          off += (size_t)B_ * TOPK_ * D_ * 4;
    unsigned short* Kh   = (unsigned short*)(ws + off); off += (size_t)1024 * D_ * 2;
    unsigned short* Kl   = (unsigned short*)(ws + off); off += (size_t)1024 * D_ * 2;
    unsigned short* WqTh = (unsigned short*)(ws + off); off += (size_t)D_ * D_ * 2;
    unsigned short* WqTl = (unsigned short*)(ws + off); off += (size_t)D_ * D_ * 2;
    unsigned short* WkTh = (unsigned short*)(ws + off); off += (size_t)D_ * D_ * 2;
    unsigned short* WkTl = (unsigned short*)(ws + off); off += (size_t)D_ * D_ * 2;
    unsigned short* Sh   = (unsigned short*)(ws + off); off += (size_t)1024 * D_ * 2;
    unsigned short* Sl   = (unsigned short*)(ws + off); off += (size_t)1024 * D_ * 2;
    unsigned short* qhb  = (unsigned short*)(ws + off);
    const size_t fixed_bytes = off;
    const size_t q_plane_b = (size_t)L_ * D_ * 2;   // one bf16 plane per batch

    int nb_fit = 1;
    if (ws_size > fixed_bytes) {
        size_t f = (ws_size - fixed_bytes) / (2 * q_plane_b);
        nb_fit = (f < 1) ? 1 : (f > 8 ? 8 : (int)f);
    }

    hipMemsetAsync(tmps, 0, (size_t)B_ * H_ * S_ * sizeof(float), stream);

    split_src_kernel<<<(1024 * D_) / (256 * 4), 256, 0, stream>>>(src, Sh, Sl);
    {
        dim3 g(D_ / 64, D_ / 64);
        splitWT_kernel<<<g, 256, 0, stream>>>(Wq, WqTh, WqTl);
        splitWT_kernel<<<g, 256, 0, stream>>>(Wk, WkTh, WkTl);
    }

    // K = src @ Wk + bk via 3-term MFMA (writes Kbuf f32 + Kh/Kl bf16)
    kproj_kernel<<<64, 256, 0, stream>>>(Sh, Sl, WkTh, WkTl, bk, Kbuf, Kh, Kl);

    for (int b0 = 0; b0 < B_; b0 += nb_fit) {
        int nb = (B_ - b0 < nb_fit) ? (B_ - b0) : nb_fit;
        unsigned short* qlb = qhb + (size_t)nb_fit * q_plane_b / 2;
        qproj_kernel<<<nb * 128, 256, 0, stream>>>(
            tgt + (size_t)b0 * L_ * D_, WqTh, WqTl, bq, qhb, qlb);
        scores2p_kernel<<<nb * 128, 256, 0, stream>>>(qhb, qlb, Kh, Kl, tmps, b0);
    }

    topk_kernel<<<B_ * H_, 256, 0, stream>>>(tmps, idxs);
    gather_kernel<<<(B_ * TOPK_ * D_ + 255) / 256, 256, 0, stream>>>(Kbuf, idxs, tok);
    {
        dim3 g(D_ / 64, (B_ * TOPK_ + 63) / 64);
        gemm_bias_kernel<<<g, 256, 0, stream>>>(tok, Wo, bo, out, B_ * TOPK_, D_, D_);
    }
}

// Round 6
// 472.717 us; speedup vs baseline: 1.3506x; 1.3506x over previous
//
#include <hip/hip_runtime.h>
#include <hip/hip_bf16.h>
#include <math.h>

// Problem constants
constexpr int B_ = 8;
constexpr int L_ = 2048;
constexpr int S_ = 1000;
constexpr int D_ = 1024;
constexpr int H_ = 8;
constexpr int E_ = 128;     // D/H
constexpr int TOPK_ = 10;
// (1/sqrt(E)) * log2(e): scores in log2 domain so p = exp2(sc)
constexpr float SCALE_LOG2E_ = 0.12751744f;

typedef __attribute__((ext_vector_type(8))) short short8;   // 8 x bf16 (4 VGPRs)
typedef __attribute__((ext_vector_type(4))) float f32x4;

__device__ inline unsigned short f2bf(float x) {            // RTN-even f32->bf16
    unsigned u = __float_as_uint(x);
    unsigned r = (u + 0x7fffu + ((u >> 16) & 1u)) >> 16;
    return (unsigned short)r;
}
__device__ inline float bf2f(unsigned short s) {
    return __uint_as_float(((unsigned)s) << 16);
}

// global -> LDS direct DMA, 16 bytes per lane (m97/m173 pattern).
// LDS dest must be wave-uniform base + lane*16 (linear); swizzle is applied
// by pre-swizzling the per-lane GLOBAL address.
typedef __attribute__((address_space(1))) const unsigned int gas_u32;
typedef __attribute__((address_space(3))) unsigned int las_u32;
__device__ __forceinline__ void gload_lds16(const void* g, void* l) {
    __builtin_amdgcn_global_load_lds((gas_u32*)g, (las_u32*)l, 16, 0, 0);
}

// ---------------------------------------------------------------------------
// Generic f32 GEMM + bias (used only for the tiny 80x1024 output GEMM)
// ---------------------------------------------------------------------------
__global__ __launch_bounds__(256) void gemm_bias_kernel(
    const float* __restrict__ A, const float* __restrict__ Bm,
    const float* __restrict__ bias, float* __restrict__ C,
    int M, int N, int Kd)
{
    __shared__ float As[16][65];
    __shared__ float Bs[16][68];

    const int t  = threadIdx.x;
    const int tx = t & 15;
    const int ty = t >> 4;
    const int m0 = blockIdx.y * 64;
    const int n0 = blockIdx.x * 64;

    float acc[4][4];
#pragma unroll
    for (int i = 0; i < 4; ++i)
#pragma unroll
        for (int j = 0; j < 4; ++j) acc[i][j] = 0.f;

    for (int k0 = 0; k0 < Kd; k0 += 16) {
        {
            const int row = t >> 2;
            const int c4  = (t & 3) * 4;
            float4 v = {0.f, 0.f, 0.f, 0.f};
            if (m0 + row < M)
                v = *(const float4*)&A[(size_t)(m0 + row) * Kd + k0 + c4];
            As[c4 + 0][row] = v.x;
            As[c4 + 1][row] = v.y;
            As[c4 + 2][row] = v.z;
            As[c4 + 3][row] = v.w;
        }
        {
            const int row = t >> 4;
            const int c4  = (t & 15) * 4;
            float4 v = *(const float4*)&Bm[(size_t)(k0 + row) * N + n0 + c4];
            *(float4*)&Bs[row][c4] = v;
        }
        __syncthreads();
#pragma unroll
        for (int k = 0; k < 16; ++k) {
            float a[4], b[4];
#pragma unroll
            for (int i = 0; i < 4; ++i) a[i] = As[k][ty * 4 + i];
            float4 bv = *(const float4*)&Bs[k][tx * 4];
            b[0] = bv.x; b[1] = bv.y; b[2] = bv.z; b[3] = bv.w;
#pragma unroll
            for (int i = 0; i < 4; ++i)
#pragma unroll
                for (int j = 0; j < 4; ++j) acc[i][j] += a[i] * b[j];
        }
        __syncthreads();
    }

#pragma unroll
    for (int i = 0; i < 4; ++i) {
        const int row = m0 + ty * 4 + i;
        if (row < M) {
#pragma unroll
            for (int j = 0; j < 4; ++j) {
                const int col = n0 + tx * 4 + j;
                C[(size_t)row * N + col] = acc[i][j] + bias[col];
            }
        }
    }
}

// ---------------------------------------------------------------------------
// WT split (transpose + hi/lo): WTh/WTl[n][k] = split(W[k][n]). (r2-proven)
// ---------------------------------------------------------------------------
__global__ __launch_bounds__(256) void splitWT_kernel(
    const float* __restrict__ W,
    unsigned short* __restrict__ WTh, unsigned short* __restrict__ WTl)
{
    __shared__ __attribute__((aligned(16))) float tile[64][68];
    const int t  = threadIdx.x;
    const int k0 = blockIdx.y * 64, n0 = blockIdx.x * 64;
#pragma unroll
    for (int it = 0; it < 4; ++it) {
        int id = it * 256 + t;
        int r = id >> 4, c = id & 15;
        *(float4*)&tile[r][c * 4] = *(const float4*)&W[(size_t)(k0 + r) * D_ + n0 + c * 4];
    }
    __syncthreads();
#pragma unroll
    for (int it = 0; it < 4; ++it) {
        int id = it * 256 + t;
        int n = id >> 4, c = id & 15;
        unsigned short hs[4], ls[4];
#pragma unroll
        for (int i = 0; i < 4; ++i) {
            float x = tile[c * 4 + i][n];
            hs[i] = f2bf(x);
            ls[i] = f2bf(x - bf2f(hs[i]));
        }
        size_t o = (size_t)(n0 + n) * D_ + k0 + c * 4;
        uint2 uh; uh.x = (unsigned)hs[0] | ((unsigned)hs[1] << 16);
                  uh.y = (unsigned)hs[2] | ((unsigned)hs[3] << 16);
        uint2 ul; ul.x = (unsigned)ls[0] | ((unsigned)ls[1] << 16);
                  ul.y = (unsigned)ls[2] | ((unsigned)ls[3] << 16);
        *(uint2*)&WTh[o] = uh;
        *(uint2*)&WTl[o] = ul;
    }
}

// ---------------------------------------------------------------------------
// src split: Sh/Sl[1024(pad)][1024] bf16 hi/lo; rows >= 1000 zeroed.
// ---------------------------------------------------------------------------
__global__ __launch_bounds__(256) void split_src_kernel(
    const float* __restrict__ src,
    unsigned short* __restrict__ Sh, unsigned short* __restrict__ Sl)
{
    int idx  = blockIdx.x * 256 + threadIdx.x;
    int base = idx * 4;
    int row  = base >> 10;
    float4 v = {0.f, 0.f, 0.f, 0.f};
    if (row < S_) v = *(const float4*)&src[base];
    float xs[4] = {v.x, v.y, v.z, v.w};
    unsigned short hs[4], ls[4];
#pragma unroll
    for (int i = 0; i < 4; ++i) {
        hs[i] = f2bf(xs[i]);
        ls[i] = f2bf(xs[i] - bf2f(hs[i]));
    }
    uint2 uh; uh.x = (unsigned)hs[0] | ((unsigned)hs[1] << 16);
              uh.y = (unsigned)hs[2] | ((unsigned)hs[3] << 16);
    uint2 ul; ul.x = (unsigned)ls[0] | ((unsigned)ls[1] << 16);
              ul.y = (unsigned)ls[2] | ((unsigned)ls[3] << 16);
    *(uint2*)&Sh[base] = uh;
    *(uint2*)&Sl[base] = ul;
}

// ---------------------------------------------------------------------------
// K projection via 3-term split-bf16 MFMA (r5-proven).
// Writes Kbuf (f32, path to output) AND Kh/Kl (bf16 hi/lo, pad rows zeroed).
// ---------------------------------------------------------------------------
__global__ __launch_bounds__(256, 2) void kproj_kernel(
    const unsigned short* __restrict__ Sh, const unsigned short* __restrict__ Sl,
    const unsigned short* __restrict__ WkTh, const unsigned short* __restrict__ WkTl,
    const float* __restrict__ bk,
    float* __restrict__ Kbuf,
    unsigned short* __restrict__ Kh, unsigned short* __restrict__ Kl)
{
    __shared__ __attribute__((aligned(16))) unsigned short Ah[128 * 64];
    __shared__ __attribute__((aligned(16))) unsigned short Al[128 * 64];
    __shared__ __attribute__((aligned(16))) unsigned short Bh[128 * 64];
    __shared__ __attribute__((aligned(16))) unsigned short Bl[128 * 64];

    const int t    = threadIdx.x;
    const int lane = t & 63, w = t >> 6;
    const int mb   = blockIdx.x >> 3;
    const int n0   = (blockIdx.x & 7) * 128;

    f32x4 acc[2][8];
#pragma unroll
    for (int m = 0; m < 2; ++m)
#pragma unroll
        for (int n = 0; n < 8; ++n) acc[m][n] = (f32x4){0.f, 0.f, 0.f, 0.f};

    for (int k0 = 0; k0 < D_; k0 += 64) {
        __syncthreads();
#pragma unroll
        for (int it = 0; it < 4; ++it) {
            int id = it * 256 + t;
            int r = id >> 3, c = id & 7;
            int lofs = r * 64 + ((c ^ (r & 7)) << 3);
            size_t ga = (size_t)(mb * 128 + r) * D_ + k0 + c * 8;
            *(uint4*)&Ah[lofs] = *(const uint4*)&Sh[ga];
            *(uint4*)&Al[lofs] = *(const uint4*)&Sl[ga];
            size_t gb = (size_t)(n0 + r) * D_ + k0 + c * 8;
            *(uint4*)&Bh[lofs] = *(const uint4*)&WkTh[gb];
            *(uint4*)&Bl[lofs] = *(const uint4*)&WkTl[gb];
        }
        __syncthreads();

#pragma unroll
        for (int ki = 0; ki < 2; ++ki) {
            short8 ah[2], al[2];
#pragma unroll
            for (int m = 0; m < 2; ++m) {
                int r = w * 32 + m * 16 + (lane & 15);
                int slot = ki * 4 + (lane >> 4);
                int lofs = r * 64 + ((slot ^ (r & 7)) << 3);
                ah[m] = *(short8*)&Ah[lofs];
                al[m] = *(short8*)&Al[lofs];
            }
#pragma unroll
            for (int n = 0; n < 8; ++n) {
                int nn = n * 16 + (lane & 15);
                int slot = ki * 4 + (lane >> 4);
                int lofs = nn * 64 + ((slot ^ (nn & 7)) << 3);
                short8 bh = *(short8*)&Bh[lofs];
                short8 bl = *(short8*)&Bl[lofs];
#pragma unroll
                for (int m = 0; m < 2; ++m) {
                    acc[m][n] = __builtin_amdgcn_mfma_f32_16x16x32_bf16(ah[m], bh, acc[m][n], 0, 0, 0);
                    acc[m][n] = __builtin_amdgcn_mfma_f32_16x16x32_bf16(ah[m], bl, acc[m][n], 0, 0, 0);
                    acc[m][n] = __builtin_amdgcn_mfma_f32_16x16x32_bf16(al[m], bh, acc[m][n], 0, 0, 0);
                }
            }
        }
    }

#pragma unroll
    for (int n = 0; n < 8; ++n) {
        int col = n0 + n * 16 + (lane & 15);
        float bkv = bk[col];
#pragma unroll
        for (int m = 0; m < 2; ++m) {
            int rbase = mb * 128 + w * 32 + m * 16 + ((lane >> 4) << 2);
#pragma unroll
            for (int r = 0; r < 4; ++r) {
                int row = rbase + r;
                unsigned short hh = 0, ll = 0;
                if (row < S_) {
                    float kv = acc[m][n][r] + bkv;
                    Kbuf[(size_t)row * D_ + col] = kv;
                    hh = f2bf(kv);
                    ll = f2bf(kv - bf2f(hh));
                }
                Kh[(size_t)row * D_ + col] = hh;
                Kl[(size_t)row * D_ + col] = ll;
            }
        }
    }
}

// ---------------------------------------------------------------------------
// Q projection, 3-term split (r4-proven form: simple 2-barrier loop, hi/lo
// split of tgt at staging time). Output: planar q hi/lo bf16, scale baked in.
// ---------------------------------------------------------------------------
__global__ __launch_bounds__(256, 2) void qproj_kernel(
    const float* __restrict__ tgt,   // pre-offset to chunk start
    const unsigned short* __restrict__ WqTh, const unsigned short* __restrict__ WqTl,
    const float* __restrict__ bq,
    unsigned short* __restrict__ qhb, unsigned short* __restrict__ qlb)
{
    __shared__ __attribute__((aligned(16))) unsigned short Ah[128 * 64];
    __shared__ __attribute__((aligned(16))) unsigned short Al[128 * 64];
    __shared__ __attribute__((aligned(16))) unsigned short Bh[128 * 64];
    __shared__ __attribute__((aligned(16))) unsigned short Bl[128 * 64];

    const int t    = threadIdx.x;
    const int lane = t & 63, w = t >> 6;
    const int mb   = blockIdx.x >> 3;
    const int n0   = (blockIdx.x & 7) * 128;

    f32x4 acc[2][8];
#pragma unroll
    for (int m = 0; m < 2; ++m)
#pragma unroll
        for (int n = 0; n < 8; ++n) acc[m][n] = (f32x4){0.f, 0.f, 0.f, 0.f};

    for (int k0 = 0; k0 < D_; k0 += 64) {
        __syncthreads();
#pragma unroll
        for (int it = 0; it < 4; ++it) {
            int id = it * 256 + t;
            int r = id >> 3, c = id & 7;
            int lofs = r * 64 + ((c ^ (r & 7)) << 3);
            // A: load 8 f32 of tgt, split hi/lo at staging time
            const float* ga = &tgt[(size_t)(mb * 128 + r) * D_ + k0 + c * 8];
            float4 v0 = *(const float4*)ga;
            float4 v1 = *(const float4*)(ga + 4);
            float xs[8] = {v0.x, v0.y, v0.z, v0.w, v1.x, v1.y, v1.z, v1.w};
            unsigned short hs[8], ls[8];
#pragma unroll
            for (int j = 0; j < 8; ++j) {
                hs[j] = f2bf(xs[j]);
                ls[j] = f2bf(xs[j] - bf2f(hs[j]));
            }
            uint4 uh, ul;
            uh.x = (unsigned)hs[0] | ((unsigned)hs[1] << 16);
            uh.y = (unsigned)hs[2] | ((unsigned)hs[3] << 16);
            uh.z = (unsigned)hs[4] | ((unsigned)hs[5] << 16);
            uh.w = (unsigned)hs[6] | ((unsigned)hs[7] << 16);
            ul.x = (unsigned)ls[0] | ((unsigned)ls[1] << 16);
            ul.y = (unsigned)ls[2] | ((unsigned)ls[3] << 16);
            ul.z = (unsigned)ls[4] | ((unsigned)ls[5] << 16);
            ul.w = (unsigned)ls[6] | ((unsigned)ls[7] << 16);
            *(uint4*)&Ah[lofs] = uh;
            *(uint4*)&Al[lofs] = ul;
            // B copy (already bf16 hi/lo)
            size_t gb = (size_t)(n0 + r) * D_ + k0 + c * 8;
            *(uint4*)&Bh[lofs] = *(const uint4*)&WqTh[gb];
            *(uint4*)&Bl[lofs] = *(const uint4*)&WqTl[gb];
        }
        __syncthreads();

#pragma unroll
        for (int ki = 0; ki < 2; ++ki) {
            short8 ah[2], al[2];
#pragma unroll
            for (int m = 0; m < 2; ++m) {
                int r = w * 32 + m * 16 + (lane & 15);
                int slot = ki * 4 + (lane >> 4);
                int lofs = r * 64 + ((slot ^ (r & 7)) << 3);
                ah[m] = *(short8*)&Ah[lofs];
                al[m] = *(short8*)&Al[lofs];
            }
#pragma unroll
            for (int n = 0; n < 8; ++n) {
                int nn = n * 16 + (lane & 15);
                int slot = ki * 4 + (lane >> 4);
                int lofs = nn * 64 + ((slot ^ (nn & 7)) << 3);
                short8 bh = *(short8*)&Bh[lofs];
                short8 bl = *(short8*)&Bl[lofs];
#pragma unroll
                for (int m = 0; m < 2; ++m) {
                    acc[m][n] = __builtin_amdgcn_mfma_f32_16x16x32_bf16(ah[m], bh, acc[m][n], 0, 0, 0);
                    acc[m][n] = __builtin_amdgcn_mfma_f32_16x16x32_bf16(ah[m], bl, acc[m][n], 0, 0, 0);
                    acc[m][n] = __builtin_amdgcn_mfma_f32_16x16x32_bf16(al[m], bh, acc[m][n], 0, 0, 0);
                }
            }
        }
    }

#pragma unroll
    for (int n = 0; n < 8; ++n) {
        int col = n0 + n * 16 + (lane & 15);
        float bqv = bq[col];
#pragma unroll
        for (int m = 0; m < 2; ++m) {
            int rbase = mb * 128 + w * 32 + m * 16 + ((lane >> 4) << 2);
#pragma unroll
            for (int r = 0; r < 4; ++r) {
                float q = (acc[m][n][r] + bqv) * SCALE_LOG2E_;
                unsigned short hh = f2bf(q);
                qhb[(size_t)(rbase + r) * D_ + col] = hh;
                qlb[(size_t)(rbase + r) * D_ + col] = f2bf(q - bf2f(hh));
            }
        }
    }
}

// ---------------------------------------------------------------------------
// Scores, 2-pass, 3-term split (r4-proven numerics), K staged via
// global_load_lds double-buffer: LDS dest linear (wave-uniform base +
// lane*16), swizzle applied by pre-swizzling the per-lane GLOBAL address
// (LDS chunk c receives global chunk c ^ (r&15); read side unchanged).
// One barrier per tile; tile u+1's DMA flies under tile u's 96 MFMAs.
// ---------------------------------------------------------------------------
__global__ __launch_bounds__(256, 2) void scores2p_kernel(
    const unsigned short* __restrict__ qhb, const unsigned short* __restrict__ qlb,
    const unsigned short* __restrict__ Kh, const unsigned short* __restrict__ Kl,
    float* __restrict__ tmps, int b0)
{
    __shared__ __attribute__((aligned(16))) unsigned short SH[2][64 * 128];
    __shared__ __attribute__((aligned(16))) unsigned short SL[2][64 * 128];
    __shared__ float tmps_l[1024];

    const int t    = threadIdx.x;
    const int lane = t & 63, w = t >> 6;
    const int blk  = blockIdx.x;
    const int bb   = blk >> 7;
    const int h    = (blk >> 4) & 7;
    const int lt   = blk & 15;
    const int qrow0 = bb * L_ + lt * 128;        // chunk-local
    const int bh_i  = (b0 + bb) * H_ + h;
    const int kr0   = t >> 4;       // staging: r = it*16 + kr0, chunk c = t&15
    const int kc0   = t & 15;

    for (int i = t; i < 1024; i += 256) tmps_l[i] = 0.f;

    // issue K-tile ST into buffer BUF via global->LDS DMA (8 issues/thread)
#define SC_ISSUE(ST, BUF)                                                   \
    do {                                                                    \
        _Pragma("unroll")                                                   \
        for (int it = 0; it < 4; ++it) {                                    \
            int r = it * 16 + kr0;                                          \
            size_t g = (size_t)((ST) * 64 + r) * D_ + h * E_                \
                       + ((kc0 ^ (r & 15)) << 3);                           \
            int lofs = it * 4096 + t * 16;  /* bytes, linear per wave */    \
            gload_lds16(&Kh[g], (char*)&SH[(BUF)][0] + lofs);               \
            gload_lds16(&Kl[g], (char*)&SL[(BUF)][0] + lofs);               \
        }                                                                   \
    } while (0)

    SC_ISSUE(0, 1);                  // tile 0 DMA flies under Q staging

    // ---- stage Q (128 rows x 128 cols, hi/lo) via SH[0]/SL[0]; hoist frags
    short8 qh[2][4], ql[2][4];
#pragma unroll
    for (int hf = 0; hf < 2; ++hf) {
        __syncthreads();
#pragma unroll
        for (int it = 0; it < 4; ++it) {
            int r = it * 16 + kr0;
            size_t g = (size_t)(qrow0 + hf * 64 + r) * D_ + h * E_ + kc0 * 8;
            int lofs = r * 128 + ((kc0 ^ (r & 15)) << 3);
            *(uint4*)&SH[0][lofs] = *(const uint4*)&qhb[g];
            *(uint4*)&SL[0][lofs] = *(const uint4*)&qlb[g];
        }
        __syncthreads();
        if ((w >> 1) == hf) {
#pragma unroll
            for (int rg = 0; rg < 2; ++rg)
#pragma unroll
                for (int ki = 0; ki < 4; ++ki) {
                    int rq = (w & 1) * 32 + rg * 16 + (lane & 15);
                    int slot = ki * 4 + (lane >> 4);
                    int lofs = rq * 128 + ((slot ^ (rq & 15)) << 3);
                    qh[rg][ki] = *(short8*)&SH[0][lofs];
                    ql[rg][ki] = *(short8*)&SL[0][lofs];
                }
        }
    }

    float zacc[2][4];
#pragma unroll
    for (int rg = 0; rg < 2; ++rg)
#pragma unroll
        for (int r = 0; r < 4; ++r) zacc[rg][r] = 0.f;
    float invZ[2][4];

    int cur = 1;                      // tile 0 landed in buffer 1
    for (int u = 0; u < 32; ++u) {
        const int st = u & 15;
        __syncthreads();              // drains DMA -> buf[cur] ready; prior
                                      // compute on buf[cur^1] finished
        if (u < 31) SC_ISSUE((u + 1) & 15, cur ^ 1);

        f32x4 acc[2][4];
#pragma unroll
        for (int rg = 0; rg < 2; ++rg)
#pragma unroll
            for (int nf = 0; nf < 4; ++nf) acc[rg][nf] = (f32x4){0.f, 0.f, 0.f, 0.f};

#pragma unroll
        for (int ki = 0; ki < 4; ++ki)
#pragma unroll
            for (int nf = 0; nf < 4; ++nf) {
                int sr = nf * 16 + (lane & 15);
                int slot = ki * 4 + (lane >> 4);
                int lofs = sr * 128 + ((slot ^ (sr & 15)) << 3);
                short8 bh = *(short8*)&SH[cur][lofs];
                short8 bl = *(short8*)&SL[cur][lofs];
#pragma unroll
                for (int rg = 0; rg < 2; ++rg) {
                    acc[rg][nf] = __builtin_amdgcn_mfma_f32_16x16x32_bf16(qh[rg][ki], bh, acc[rg][nf], 0, 0, 0);
                    acc[rg][nf] = __builtin_amdgcn_mfma_f32_16x16x32_bf16(qh[rg][ki], bl, acc[rg][nf], 0, 0, 0);
                    acc[rg][nf] = __builtin_amdgcn_mfma_f32_16x16x32_bf16(ql[rg][ki], bh, acc[rg][nf], 0, 0, 0);
                }
            }

        if (u < 16) {                 // pass 0: accumulate Z
#pragma unroll
            for (int nf = 0; nf < 4; ++nf) {
                int s = st * 64 + nf * 16 + (lane & 15);
                if (s < S_) {
#pragma unroll
                    for (int rg = 0; rg < 2; ++rg)
#pragma unroll
                        for (int r = 0; r < 4; ++r)
                            zacc[rg][r] += exp2f(acc[rg][nf][r]);
                }
            }
            if (u == 15) {
#pragma unroll
                for (int rg = 0; rg < 2; ++rg)
#pragma unroll
                    for (int r = 0; r < 4; ++r) {
                        float z = zacc[rg][r];
                        z += __shfl_xor(z, 1);
                        z += __shfl_xor(z, 2);
                        z += __shfl_xor(z, 4);
                        z += __shfl_xor(z, 8);
                        invZ[rg][r] = 1.f / z;
                    }
            }
        } else {                      // pass 1: p * invZ -> tmps_l
#pragma unroll
            for (int nf = 0; nf < 4; ++nf) {
                int s = st * 64 + nf * 16 + (lane & 15);
                if (s < S_) {
                    float val = 0.f;
#pragma unroll
                    for (int rg = 0; rg < 2; ++rg)
#pragma unroll
                        for (int r = 0; r < 4; ++r)
                            val += exp2f(acc[rg][nf][r]) * invZ[rg][r];
                    atomicAdd(&tmps_l[s], val);
                }
            }
        }
        cur ^= 1;
    }
#undef SC_ISSUE

    __syncthreads();
    for (int i = t; i < S_; i += 256)
        atomicAdd(&tmps[(size_t)bh_i * S_ + i], tmps_l[i]);
}

// ---------------------------------------------------------------------------
// Top-k (k=10) per (b,h); ties -> smaller index (matches jax.lax.top_k).
// ---------------------------------------------------------------------------
__global__ __launch_bounds__(256) void topk_kernel(
    const float* __restrict__ tmps, int* __restrict__ idxs)
{
    const int bh = blockIdx.x;
    const int t  = threadIdx.x;
    __shared__ float v[S_];
    __shared__ float rv[256];
    __shared__ int   ri[256];

    for (int i = t; i < S_; i += 256) v[i] = tmps[(size_t)bh * S_ + i];
    __syncthreads();

    for (int it = 0; it < TOPK_; ++it) {
        float best = -1e38f;
        int bi = 0x7fffffff;
        for (int s = t; s < S_; s += 256) {
            const float x = v[s];
            if (x > best) { best = x; bi = s; }
        }
        rv[t] = best; ri[t] = bi;
        __syncthreads();
        for (int k = 128; k > 0; k >>= 1) {
            if (t < k) {
                const float x = rv[t + k];
                const int  xi = ri[t + k];
                if (x > rv[t] || (x == rv[t] && xi < ri[t])) { rv[t] = x; ri[t] = xi; }
            }
            __syncthreads();
        }
        if (t == 0) {
            idxs[bh * TOPK_ + it] = ri[0];
            v[ri[0]] = -1e38f;
        }
        __syncthreads();
    }
}

// ---------------------------------------------------------------------------
// Gather selected K rows into tok[b][topk][D]
// ---------------------------------------------------------------------------
__global__ __launch_bounds__(256) void gather_kernel(
    const float* __restrict__ K, const int* __restrict__ idxs,
    float* __restrict__ tok)
{
    const int o = blockIdx.x * 256 + threadIdx.x;
    if (o >= B_ * TOPK_ * D_) return;
    const int d  = o & (D_ - 1);
    const int tt = (o >> 10) % TOPK_;
    const int b  = o / (D_ * TOPK_);
    const int h  = d >> 7;
    const int s  = idxs[(b * H_ + h) * TOPK_ + tt];
    tok[o] = K[(size_t)s * D_ + d];
}

// ---------------------------------------------------------------------------
extern "C" void kernel_launch(void* const* d_in, const int* in_sizes, int n_in,
                              void* d_out, int out_size, void* d_ws, size_t ws_size,
                              hipStream_t stream)
{
    const float* tgt = (const float*)d_in[0];
    const float* src = (const float*)d_in[1];
    const float* Wq  = (const float*)d_in[2];
    const float* bq  = (const float*)d_in[3];
    const float* Wk  = (const float*)d_in[4];
    const float* bk  = (const float*)d_in[5];
    const float* Wo  = (const float*)d_in[6];
    const float* bo  = (const float*)d_in[7];
    float* out = (float*)d_out;

    // workspace layout (bytes, all 256-aligned)
    char* ws = (char*)d_ws;
    size_t off = 0;
    float*          Kbuf = (float*)(ws + off);          off += (size_t)S_ * D_ * 4;
    float*          tmps = (float*)(ws + off);          off += (size_t)B_ * H_ * S_ * 4;
    int*            idxs = (int*)(ws + off);            off += (size_t)B_ * H_ * TOPK_ * 4;
    off = (off + 255) & ~(size_t)255;
    float*          tok  = (float*)(ws + off);          off += (size_t)B_ * TOPK_ * D_ * 4;
    unsigned short* Kh   = (unsigned short*)(ws + off); off += (size_t)1024 * D_ * 2;
    unsigned short* Kl   = (unsigned short*)(ws + off); off += (size_t)1024 * D_ * 2;
    unsigned short* WqTh = (unsigned short*)(ws + off); off += (size_t)D_ * D_ * 2;
    unsigned short* WqTl = (unsigned short*)(ws + off); off += (size_t)D_ * D_ * 2;
    unsigned short* WkTh = (unsigned short*)(ws + off); off += (size_t)D_ * D_ * 2;
    unsigned short* WkTl = (unsigned short*)(ws + off); off += (size_t)D_ * D_ * 2;
    unsigned short* Sh   = (unsigned short*)(ws + off); off += (size_t)1024 * D_ * 2;
    unsigned short* Sl   = (unsigned short*)(ws + off); off += (size_t)1024 * D_ * 2;
    unsigned short* qhb  = (unsigned short*)(ws + off);
    const size_t fixed_bytes = off;
    const size_t q_plane_b = (size_t)L_ * D_ * 2;   // one bf16 plane per batch

    int nb_fit = 1;
    if (ws_size > fixed_bytes) {
        size_t f = (ws_size - fixed_bytes) / (2 * q_plane_b);
        nb_fit = (f < 1) ? 1 : (f > 8 ? 8 : (int)f);
    }

    hipMemsetAsync(tmps, 0, (size_t)B_ * H_ * S_ * sizeof(float), stream);

    split_src_kernel<<<(1024 * D_) / (256 * 4), 256, 0, stream>>>(src, Sh, Sl);
    {
        dim3 g(D_ / 64, D_ / 64);
        splitWT_kernel<<<g, 256, 0, stream>>>(Wq, WqTh, WqTl);
        splitWT_kernel<<<g, 256, 0, stream>>>(Wk, WkTh, WkTl);
    }

    // K = src @ Wk + bk via 3-term MFMA (writes Kbuf f32 + Kh/Kl bf16)
    kproj_kernel<<<64, 256, 0, stream>>>(Sh, Sl, WkTh, WkTl, bk, Kbuf, Kh, Kl);

    for (int b0 = 0; b0 < B_; b0 += nb_fit) {
        int nb = (B_ - b0 < nb_fit) ? (B_ - b0) : nb_fit;
        unsigned short* qlb = qhb + (size_t)nb_fit * q_plane_b / 2;
        qproj_kernel<<<nb * 128, 256, 0, stream>>>(
            tgt + (size_t)b0 * L_ * D_, WqTh, WqTl, bq, qhb, qlb);
        scores2p_kernel<<<nb * 128, 256, 0, stream>>>(qhb, qlb, Kh, Kl, tmps, b0);
    }

    topk_kernel<<<B_ * H_, 256, 0, stream>>>(tmps, idxs);
    gather_kernel<<<(B_ * TOPK_ * D_ + 255) / 256, 256, 0, stream>>>(Kbuf, idxs, tok);
    {
        dim3 g(D_ / 64, (B_ * TOPK_ + 63) / 64);
        gemm_bias_kernel<<<g, 256, 0, stream>>>(tok, Wo, bo, out, B_ * TOPK_, D_, D_);
    }
}

// Round 7
// 447.701 us; speedup vs baseline: 1.4261x; 1.0559x over previous
//
#include <hip/hip_runtime.h>
#include <hip/hip_bf16.h>
#include <math.h>

// Problem constants
constexpr int B_ = 8;
constexpr int L_ = 2048;
constexpr int S_ = 1000;
constexpr int D_ = 1024;
constexpr int H_ = 8;
constexpr int E_ = 128;     // D/H
constexpr int TOPK_ = 10;
// (1/sqrt(E)) * log2(e): scores in log2 domain so p = exp2(sc)
constexpr float SCALE_LOG2E_ = 0.12751744f;

typedef __attribute__((ext_vector_type(8))) short short8;   // 8 x bf16 (4 VGPRs)
typedef __attribute__((ext_vector_type(4))) float f32x4;

__device__ inline unsigned short f2bf(float x) {            // RTN-even f32->bf16
    unsigned u = __float_as_uint(x);
    unsigned r = (u + 0x7fffu + ((u >> 16) & 1u)) >> 16;
    return (unsigned short)r;
}
__device__ inline float bf2f(unsigned short s) {
    return __uint_as_float(((unsigned)s) << 16);
}

// fast 2^x (raw v_exp_f32; no libm range fixups — inputs are |x| < 60 here)
__device__ __forceinline__ float fexp2(float x) {
#if __has_builtin(__builtin_amdgcn_exp2f)
    return __builtin_amdgcn_exp2f(x);
#else
    return __expf(x * 0.69314718056f);
#endif
}

// global -> LDS direct DMA, 16 bytes per lane (m97/m173 pattern).
// LDS dest must be wave-uniform base + lane*16 (linear); swizzle is applied
// by pre-swizzling the per-lane GLOBAL address (same involution as the read).
typedef __attribute__((address_space(1))) const unsigned int gas_u32;
typedef __attribute__((address_space(3))) unsigned int las_u32;
__device__ __forceinline__ void gload_lds16(const void* g, void* l) {
    __builtin_amdgcn_global_load_lds((gas_u32*)g, (las_u32*)l, 16, 0, 0);
}

// ---------------------------------------------------------------------------
// Generic f32 GEMM + bias (used only for the tiny 80x1024 output GEMM)
// ---------------------------------------------------------------------------
__global__ __launch_bounds__(256) void gemm_bias_kernel(
    const float* __restrict__ A, const float* __restrict__ Bm,
    const float* __restrict__ bias, float* __restrict__ C,
    int M, int N, int Kd)
{
    __shared__ float As[16][65];
    __shared__ float Bs[16][68];

    const int t  = threadIdx.x;
    const int tx = t & 15;
    const int ty = t >> 4;
    const int m0 = blockIdx.y * 64;
    const int n0 = blockIdx.x * 64;

    float acc[4][4];
#pragma unroll
    for (int i = 0; i < 4; ++i)
#pragma unroll
        for (int j = 0; j < 4; ++j) acc[i][j] = 0.f;

    for (int k0 = 0; k0 < Kd; k0 += 16) {
        {
            const int row = t >> 2;
            const int c4  = (t & 3) * 4;
            float4 v = {0.f, 0.f, 0.f, 0.f};
            if (m0 + row < M)
                v = *(const float4*)&A[(size_t)(m0 + row) * Kd + k0 + c4];
            As[c4 + 0][row] = v.x;
            As[c4 + 1][row] = v.y;
            As[c4 + 2][row] = v.z;
            As[c4 + 3][row] = v.w;
        }
        {
            const int row = t >> 4;
            const int c4  = (t & 15) * 4;
            float4 v = *(const float4*)&Bm[(size_t)(k0 + row) * N + n0 + c4];
            *(float4*)&Bs[row][c4] = v;
        }
        __syncthreads();
#pragma unroll
        for (int k = 0; k < 16; ++k) {
            float a[4], b[4];
#pragma unroll
            for (int i = 0; i < 4; ++i) a[i] = As[k][ty * 4 + i];
            float4 bv = *(const float4*)&Bs[k][tx * 4];
            b[0] = bv.x; b[1] = bv.y; b[2] = bv.z; b[3] = bv.w;
#pragma unroll
            for (int i = 0; i < 4; ++i)
#pragma unroll
                for (int j = 0; j < 4; ++j) acc[i][j] += a[i] * b[j];
        }
        __syncthreads();
    }

#pragma unroll
    for (int i = 0; i < 4; ++i) {
        const int row = m0 + ty * 4 + i;
        if (row < M) {
#pragma unroll
            for (int j = 0; j < 4; ++j) {
                const int col = n0 + tx * 4 + j;
                C[(size_t)row * N + col] = acc[i][j] + bias[col];
            }
        }
    }
}

// ---------------------------------------------------------------------------
// WT split (transpose + hi/lo): WTh/WTl[n][k] = split(W[k][n]). (r2-proven)
// ---------------------------------------------------------------------------
__global__ __launch_bounds__(256) void splitWT_kernel(
    const float* __restrict__ W,
    unsigned short* __restrict__ WTh, unsigned short* __restrict__ WTl)
{
    __shared__ __attribute__((aligned(16))) float tile[64][68];
    const int t  = threadIdx.x;
    const int k0 = blockIdx.y * 64, n0 = blockIdx.x * 64;
#pragma unroll
    for (int it = 0; it < 4; ++it) {
        int id = it * 256 + t;
        int r = id >> 4, c = id & 15;
        *(float4*)&tile[r][c * 4] = *(const float4*)&W[(size_t)(k0 + r) * D_ + n0 + c * 4];
    }
    __syncthreads();
#pragma unroll
    for (int it = 0; it < 4; ++it) {
        int id = it * 256 + t;
        int n = id >> 4, c = id & 15;
        unsigned short hs[4], ls[4];
#pragma unroll
        for (int i = 0; i < 4; ++i) {
            float x = tile[c * 4 + i][n];
            hs[i] = f2bf(x);
            ls[i] = f2bf(x - bf2f(hs[i]));
        }
        size_t o = (size_t)(n0 + n) * D_ + k0 + c * 4;
        uint2 uh; uh.x = (unsigned)hs[0] | ((unsigned)hs[1] << 16);
                  uh.y = (unsigned)hs[2] | ((unsigned)hs[3] << 16);
        uint2 ul; ul.x = (unsigned)ls[0] | ((unsigned)ls[1] << 16);
                  ul.y = (unsigned)ls[2] | ((unsigned)ls[3] << 16);
        *(uint2*)&WTh[o] = uh;
        *(uint2*)&WTl[o] = ul;
    }
}

// ---------------------------------------------------------------------------
// src split: Sh/Sl[1024(pad)][1024] bf16 hi/lo; rows >= 1000 zeroed.
// ---------------------------------------------------------------------------
__global__ __launch_bounds__(256) void split_src_kernel(
    const float* __restrict__ src,
    unsigned short* __restrict__ Sh, unsigned short* __restrict__ Sl)
{
    int idx  = blockIdx.x * 256 + threadIdx.x;
    int base = idx * 4;
    int row  = base >> 10;
    float4 v = {0.f, 0.f, 0.f, 0.f};
    if (row < S_) v = *(const float4*)&src[base];
    float xs[4] = {v.x, v.y, v.z, v.w};
    unsigned short hs[4], ls[4];
#pragma unroll
    for (int i = 0; i < 4; ++i) {
        hs[i] = f2bf(xs[i]);
        ls[i] = f2bf(xs[i] - bf2f(hs[i]));
    }
    uint2 uh; uh.x = (unsigned)hs[0] | ((unsigned)hs[1] << 16);
              uh.y = (unsigned)hs[2] | ((unsigned)hs[3] << 16);
    uint2 ul; ul.x = (unsigned)ls[0] | ((unsigned)ls[1] << 16);
              ul.y = (unsigned)ls[2] | ((unsigned)ls[3] << 16);
    *(uint2*)&Sh[base] = uh;
    *(uint2*)&Sl[base] = ul;
}

// ---------------------------------------------------------------------------
// K projection via 3-term split-bf16 MFMA; all 4 input planes are pre-split
// bf16 -> staged via global_load_lds with pre-swizzled source (zero staging
// VALU). Writes Kbuf (f32, path to output) AND Kh/Kl (hi/lo, pad rows zero).
// ---------------------------------------------------------------------------
__global__ __launch_bounds__(256, 2) void kproj_kernel(
    const unsigned short* __restrict__ Sh, const unsigned short* __restrict__ Sl,
    const unsigned short* __restrict__ WkTh, const unsigned short* __restrict__ WkTl,
    const float* __restrict__ bk,
    float* __restrict__ Kbuf,
    unsigned short* __restrict__ Kh, unsigned short* __restrict__ Kl)
{
    __shared__ __attribute__((aligned(16))) unsigned short Ah[128 * 64];
    __shared__ __attribute__((aligned(16))) unsigned short Al[128 * 64];
    __shared__ __attribute__((aligned(16))) unsigned short Bh[128 * 64];
    __shared__ __attribute__((aligned(16))) unsigned short Bl[128 * 64];

    const int t    = threadIdx.x;
    const int lane = t & 63, w = t >> 6;
    const int mb   = blockIdx.x >> 3;
    const int n0   = (blockIdx.x & 7) * 128;

    f32x4 acc[2][8];
#pragma unroll
    for (int m = 0; m < 2; ++m)
#pragma unroll
        for (int n = 0; n < 8; ++n) acc[m][n] = (f32x4){0.f, 0.f, 0.f, 0.f};

    for (int k0 = 0; k0 < D_; k0 += 64) {
        __syncthreads();
#pragma unroll
        for (int it = 0; it < 4; ++it) {   // DMA all 4 planes, swizzled src
            int r = it * 32 + (t >> 3), c = t & 7;
            size_t gofs = (size_t)r * D_ + k0 + ((c ^ (r & 7)) << 3);
            int db = it * 4096 + t * 16;
            gload_lds16(&Sh[(size_t)(mb * 128) * D_ + gofs], (char*)Ah + db);
            gload_lds16(&Sl[(size_t)(mb * 128) * D_ + gofs], (char*)Al + db);
            gload_lds16(&WkTh[(size_t)n0 * D_ + gofs], (char*)Bh + db);
            gload_lds16(&WkTl[(size_t)n0 * D_ + gofs], (char*)Bl + db);
        }
        __syncthreads();

#pragma unroll
        for (int ki = 0; ki < 2; ++ki) {
            short8 ah[2], al[2];
#pragma unroll
            for (int m = 0; m < 2; ++m) {
                int r = w * 32 + m * 16 + (lane & 15);
                int slot = ki * 4 + (lane >> 4);
                int lofs = r * 64 + ((slot ^ (r & 7)) << 3);
                ah[m] = *(short8*)&Ah[lofs];
                al[m] = *(short8*)&Al[lofs];
            }
#pragma unroll
            for (int n = 0; n < 8; ++n) {
                int nn = n * 16 + (lane & 15);
                int slot = ki * 4 + (lane >> 4);
                int lofs = nn * 64 + ((slot ^ (nn & 7)) << 3);
                short8 bh = *(short8*)&Bh[lofs];
                short8 bl = *(short8*)&Bl[lofs];
#pragma unroll
                for (int m = 0; m < 2; ++m) {
                    acc[m][n] = __builtin_amdgcn_mfma_f32_16x16x32_bf16(ah[m], bh, acc[m][n], 0, 0, 0);
                    acc[m][n] = __builtin_amdgcn_mfma_f32_16x16x32_bf16(ah[m], bl, acc[m][n], 0, 0, 0);
                    acc[m][n] = __builtin_amdgcn_mfma_f32_16x16x32_bf16(al[m], bh, acc[m][n], 0, 0, 0);
                }
            }
        }
    }

#pragma unroll
    for (int n = 0; n < 8; ++n) {
        int col = n0 + n * 16 + (lane & 15);
        float bkv = bk[col];
#pragma unroll
        for (int m = 0; m < 2; ++m) {
            int rbase = mb * 128 + w * 32 + m * 16 + ((lane >> 4) << 2);
#pragma unroll
            for (int r = 0; r < 4; ++r) {
                int row = rbase + r;
                unsigned short hh = 0, ll = 0;
                if (row < S_) {
                    float kv = acc[m][n][r] + bkv;
                    Kbuf[(size_t)row * D_ + col] = kv;
                    hh = f2bf(kv);
                    ll = f2bf(kv - bf2f(hh));
                }
                Kh[(size_t)row * D_ + col] = hh;
                Kl[(size_t)row * D_ + col] = ll;
            }
        }
    }
}

// ---------------------------------------------------------------------------
// Q projection, 3-term split. B (WqT hi/lo) staged via global_load_lds
// (pre-swizzled src, overlaps A conversion); A split uses native bf16 casts
// (v_cvt_pk). Output: planar q hi/lo bf16 with SCALE*log2(e) baked in.
// ---------------------------------------------------------------------------
__global__ __launch_bounds__(256, 2) void qproj_kernel(
    const float* __restrict__ tgt,   // pre-offset to chunk start
    const unsigned short* __restrict__ WqTh, const unsigned short* __restrict__ WqTl,
    const float* __restrict__ bq,
    unsigned short* __restrict__ qhb, unsigned short* __restrict__ qlb)
{
    __shared__ __attribute__((aligned(16))) unsigned short Ah[128 * 64];
    __shared__ __attribute__((aligned(16))) unsigned short Al[128 * 64];
    __shared__ __attribute__((aligned(16))) unsigned short Bh[128 * 64];
    __shared__ __attribute__((aligned(16))) unsigned short Bl[128 * 64];

    const int t    = threadIdx.x;
    const int lane = t & 63, w = t >> 6;
    const int mb   = blockIdx.x >> 3;
    const int n0   = (blockIdx.x & 7) * 128;

    f32x4 acc[2][8];
#pragma unroll
    for (int m = 0; m < 2; ++m)
#pragma unroll
        for (int n = 0; n < 8; ++n) acc[m][n] = (f32x4){0.f, 0.f, 0.f, 0.f};

    for (int k0 = 0; k0 < D_; k0 += 64) {
        __syncthreads();
        // B planes via DMA (pre-swizzled source) — fly under A conversion
#pragma unroll
        for (int it = 0; it < 4; ++it) {
            int r = it * 32 + (t >> 3), c = t & 7;
            size_t gb = (size_t)(n0 + r) * D_ + k0 + ((c ^ (r & 7)) << 3);
            int db = it * 4096 + t * 16;
            gload_lds16(&WqTh[gb], (char*)Bh + db);
            gload_lds16(&WqTl[gb], (char*)Bl + db);
        }
        // A: load 8 f32 of tgt, split hi/lo via native casts, swizzled write
#pragma unroll
        for (int it = 0; it < 4; ++it) {
            int id = it * 256 + t;
            int r = id >> 3, c = id & 7;
            int lofs = r * 64 + ((c ^ (r & 7)) << 3);
            const float* ga = &tgt[(size_t)(mb * 128 + r) * D_ + k0 + c * 8];
            float4 v0 = *(const float4*)ga;
            float4 v1 = *(const float4*)(ga + 4);
            float xs[8] = {v0.x, v0.y, v0.z, v0.w, v1.x, v1.y, v1.z, v1.w};
            unsigned short hs[8], ls[8];
#pragma unroll
            for (int j = 0; j < 8; ++j) {
                __hip_bfloat16 hb = __float2bfloat16(xs[j]);
                hs[j] = *(unsigned short*)&hb;
                __hip_bfloat16 lb = __float2bfloat16(xs[j] - __bfloat162float(hb));
                ls[j] = *(unsigned short*)&lb;
            }
            uint4 uh, ul;
            uh.x = (unsigned)hs[0] | ((unsigned)hs[1] << 16);
            uh.y = (unsigned)hs[2] | ((unsigned)hs[3] << 16);
            uh.z = (unsigned)hs[4] | ((unsigned)hs[5] << 16);
            uh.w = (unsigned)hs[6] | ((unsigned)hs[7] << 16);
            ul.x = (unsigned)ls[0] | ((unsigned)ls[1] << 16);
            ul.y = (unsigned)ls[2] | ((unsigned)ls[3] << 16);
            ul.z = (unsigned)ls[4] | ((unsigned)ls[5] << 16);
            ul.w = (unsigned)ls[6] | ((unsigned)ls[7] << 16);
            *(uint4*)&Ah[lofs] = uh;
            *(uint4*)&Al[lofs] = ul;
        }
        __syncthreads();   // drains DMA (vmcnt) + A writes (lgkm)

#pragma unroll
        for (int ki = 0; ki < 2; ++ki) {
            short8 ah[2], al[2];
#pragma unroll
            for (int m = 0; m < 2; ++m) {
                int r = w * 32 + m * 16 + (lane & 15);
                int slot = ki * 4 + (lane >> 4);
                int lofs = r * 64 + ((slot ^ (r & 7)) << 3);
                ah[m] = *(short8*)&Ah[lofs];
                al[m] = *(short8*)&Al[lofs];
            }
#pragma unroll
            for (int n = 0; n < 8; ++n) {
                int nn = n * 16 + (lane & 15);
                int slot = ki * 4 + (lane >> 4);
                int lofs = nn * 64 + ((slot ^ (nn & 7)) << 3);
                short8 bh = *(short8*)&Bh[lofs];
                short8 bl = *(short8*)&Bl[lofs];
#pragma unroll
                for (int m = 0; m < 2; ++m) {
                    acc[m][n] = __builtin_amdgcn_mfma_f32_16x16x32_bf16(ah[m], bh, acc[m][n], 0, 0, 0);
                    acc[m][n] = __builtin_amdgcn_mfma_f32_16x16x32_bf16(ah[m], bl, acc[m][n], 0, 0, 0);
                    acc[m][n] = __builtin_amdgcn_mfma_f32_16x16x32_bf16(al[m], bh, acc[m][n], 0, 0, 0);
                }
            }
        }
    }

#pragma unroll
    for (int n = 0; n < 8; ++n) {
        int col = n0 + n * 16 + (lane & 15);
        float bqv = bq[col];
#pragma unroll
        for (int m = 0; m < 2; ++m) {
            int rbase = mb * 128 + w * 32 + m * 16 + ((lane >> 4) << 2);
#pragma unroll
            for (int r = 0; r < 4; ++r) {
                float q = (acc[m][n][r] + bqv) * SCALE_LOG2E_;
                unsigned short hh = f2bf(q);
                qhb[(size_t)(rbase + r) * D_ + col] = hh;
                qlb[(size_t)(rbase + r) * D_ + col] = f2bf(q - bf2f(hh));
            }
        }
    }
}

// ---------------------------------------------------------------------------
// Scores, 2-pass, 3-term split (r4/r6-proven numerics). K staged via
// global_load_lds double-buffer in 32-row tiles (LDS 36 KB -> 4 blocks/CU).
// 64 steps (2 passes x 32 tiles), one barrier per step; DMA of tile u+1
// flies under the 48 MFMAs of tile u. fexp2 = raw v_exp_f32.
// ---------------------------------------------------------------------------
__global__ __launch_bounds__(256, 4) void scores2p_kernel(
    const unsigned short* __restrict__ qhb, const unsigned short* __restrict__ qlb,
    const unsigned short* __restrict__ Kh, const unsigned short* __restrict__ Kl,
    float* __restrict__ tmps, int b0)
{
    __shared__ __attribute__((aligned(16))) unsigned short SH[2][32 * 128];
    __shared__ __attribute__((aligned(16))) unsigned short SL[2][32 * 128];
    __shared__ float tmps_l[1024];

    const int t    = threadIdx.x;
    const int lane = t & 63, w = t >> 6;
    const int blk  = blockIdx.x;
    const int bb   = blk >> 7;
    const int h    = (blk >> 4) & 7;
    const int lt   = blk & 15;
    const int qrow0 = bb * L_ + lt * 128;        // chunk-local
    const int bh_i  = (b0 + bb) * H_ + h;
    const int kr0   = t >> 4;       // staging: r = it*16 + kr0, chunk c = t&15
    const int kc0   = t & 15;

    for (int i = t; i < 1024; i += 256) tmps_l[i] = 0.f;

    // issue 32-row K-tile ST into buffer BUF via DMA (4 issues/thread)
#define SC_ISSUE(ST, BUF)                                                   \
    do {                                                                    \
        _Pragma("unroll")                                                   \
        for (int it = 0; it < 2; ++it) {                                    \
            int r = it * 16 + kr0;                                          \
            size_t g = (size_t)((ST) * 32 + r) * D_ + h * E_                \
                       + ((kc0 ^ (r & 15)) << 3);                           \
            int db = it * 4096 + t * 16;                                    \
            gload_lds16(&Kh[g], (char*)&SH[(BUF)][0] + db);                 \
            gload_lds16(&Kl[g], (char*)&SL[(BUF)][0] + db);                 \
        }                                                                   \
    } while (0)

    SC_ISSUE(0, 1);                  // tile 0 DMA flies under Q staging

    // ---- stage Q (128 rows x 128 cols, hi/lo) in 4 chunks of 32 rows via
    // SH[0]/SL[0]; wave w hoists its own 32 rows when chunk == w.
    short8 qh[2][4], ql[2][4];
#pragma unroll
    for (int ch = 0; ch < 4; ++ch) {
        __syncthreads();
#pragma unroll
        for (int it = 0; it < 2; ++it) {
            int r = it * 16 + kr0;
            size_t g = (size_t)(qrow0 + ch * 32 + r) * D_ + h * E_ + kc0 * 8;
            int lofs = r * 128 + ((kc0 ^ (r & 15)) << 3);
            *(uint4*)&SH[0][lofs] = *(const uint4*)&qhb[g];
            *(uint4*)&SL[0][lofs] = *(const uint4*)&qlb[g];
        }
        __syncthreads();
        if (w == ch) {
#pragma unroll
            for (int rg = 0; rg < 2; ++rg)
#pragma unroll
                for (int ki = 0; ki < 4; ++ki) {
                    int rq = rg * 16 + (lane & 15);
                    int slot = ki * 4 + (lane >> 4);
                    int lofs = rq * 128 + ((slot ^ (rq & 15)) << 3);
                    qh[rg][ki] = *(short8*)&SH[0][lofs];
                    ql[rg][ki] = *(short8*)&SL[0][lofs];
                }
        }
    }

    float zacc[2][4];
#pragma unroll
    for (int rg = 0; rg < 2; ++rg)
#pragma unroll
        for (int r = 0; r < 4; ++r) zacc[rg][r] = 0.f;
    float invZ[2][4];

    int cur = 1;                      // tile 0 landed in buffer 1
    for (int u = 0; u < 64; ++u) {
        const int st = u & 31;
        __syncthreads();              // DMA -> buf[cur] ready; prior compute
                                      // on buf[cur^1] finished
        if (u < 63) SC_ISSUE((u + 1) & 31, cur ^ 1);

        f32x4 acc[2][2];
#pragma unroll
        for (int rg = 0; rg < 2; ++rg)
#pragma unroll
            for (int nf = 0; nf < 2; ++nf) acc[rg][nf] = (f32x4){0.f, 0.f, 0.f, 0.f};

#pragma unroll
        for (int ki = 0; ki < 4; ++ki)
#pragma unroll
            for (int nf = 0; nf < 2; ++nf) {
                int sr = nf * 16 + (lane & 15);
                int slot = ki * 4 + (lane >> 4);
                int lofs = sr * 128 + ((slot ^ (sr & 15)) << 3);
                short8 bh = *(short8*)&SH[cur][lofs];
                short8 bl = *(short8*)&SL[cur][lofs];
#pragma unroll
                for (int rg = 0; rg < 2; ++rg) {
                    acc[rg][nf] = __builtin_amdgcn_mfma_f32_16x16x32_bf16(qh[rg][ki], bh, acc[rg][nf], 0, 0, 0);
                    acc[rg][nf] = __builtin_amdgcn_mfma_f32_16x16x32_bf16(qh[rg][ki], bl, acc[rg][nf], 0, 0, 0);
                    acc[rg][nf] = __builtin_amdgcn_mfma_f32_16x16x32_bf16(ql[rg][ki], bh, acc[rg][nf], 0, 0, 0);
                }
            }

        if (u < 32) {                 // pass 0: accumulate Z
#pragma unroll
            for (int nf = 0; nf < 2; ++nf) {
                int s = st * 32 + nf * 16 + (lane & 15);
                if (s < S_) {
#pragma unroll
                    for (int rg = 0; rg < 2; ++rg)
#pragma unroll
                        for (int r = 0; r < 4; ++r)
                            zacc[rg][r] += fexp2(acc[rg][nf][r]);
                }
            }
            if (u == 31) {
#pragma unroll
                for (int rg = 0; rg < 2; ++rg)
#pragma unroll
                    for (int r = 0; r < 4; ++r) {
                        float z = zacc[rg][r];
                        z += __shfl_xor(z, 1);
                        z += __shfl_xor(z, 2);
                        z += __shfl_xor(z, 4);
                        z += __shfl_xor(z, 8);
                        invZ[rg][r] = 1.f / z;
                    }
            }
        } else {                      // pass 1: p * invZ -> tmps_l
#pragma unroll
            for (int nf = 0; nf < 2; ++nf) {
                int s = st * 32 + nf * 16 + (lane & 15);
                if (s < S_) {
                    float val = 0.f;
#pragma unroll
                    for (int rg = 0; rg < 2; ++rg)
#pragma unroll
                        for (int r = 0; r < 4; ++r)
                            val += fexp2(acc[rg][nf][r]) * invZ[rg][r];
                    atomicAdd(&tmps_l[s], val);
                }
            }
        }
        cur ^= 1;
    }
#undef SC_ISSUE

    __syncthreads();
    for (int i = t; i < S_; i += 256)
        atomicAdd(&tmps[(size_t)bh_i * S_ + i], tmps_l[i]);
}

// ---------------------------------------------------------------------------
// Top-k (k=10) per (b,h); ties -> smaller index (matches jax.lax.top_k).
// ---------------------------------------------------------------------------
__global__ __launch_bounds__(256) void topk_kernel(
    const float* __restrict__ tmps, int* __restrict__ idxs)
{
    const int bh = blockIdx.x;
    const int t  = threadIdx.x;
    __shared__ float v[S_];
    __shared__ float rv[256];
    __shared__ int   ri[256];

    for (int i = t; i < S_; i += 256) v[i] = tmps[(size_t)bh * S_ + i];
    __syncthreads();

    for (int it = 0; it < TOPK_; ++it) {
        float best = -1e38f;
        int bi = 0x7fffffff;
        for (int s = t; s < S_; s += 256) {
            const float x = v[s];
            if (x > best) { best = x; bi = s; }
        }
        rv[t] = best; ri[t] = bi;
        __syncthreads();
        for (int k = 128; k > 0; k >>= 1) {
            if (t < k) {
                const float x = rv[t + k];
                const int  xi = ri[t + k];
                if (x > rv[t] || (x == rv[t] && xi < ri[t])) { rv[t] = x; ri[t] = xi; }
            }
            __syncthreads();
        }
        if (t == 0) {
            idxs[bh * TOPK_ + it] = ri[0];
            v[ri[0]] = -1e38f;
        }
        __syncthreads();
    }
}

// ---------------------------------------------------------------------------
// Gather selected K rows into tok[b][topk][D]
// ---------------------------------------------------------------------------
__global__ __launch_bounds__(256) void gather_kernel(
    const float* __restrict__ K, const int* __restrict__ idxs,
    float* __restrict__ tok)
{
    const int o = blockIdx.x * 256 + threadIdx.x;
    if (o >= B_ * TOPK_ * D_) return;
    const int d  = o & (D_ - 1);
    const int tt = (o >> 10) % TOPK_;
    const int b  = o / (D_ * TOPK_);
    const int h  = d >> 7;
    const int s  = idxs[(b * H_ + h) * TOPK_ + tt];
    tok[o] = K[(size_t)s * D_ + d];
}

// ---------------------------------------------------------------------------
extern "C" void kernel_launch(void* const* d_in, const int* in_sizes, int n_in,
                              void* d_out, int out_size, void* d_ws, size_t ws_size,
                              hipStream_t stream)
{
    const float* tgt = (const float*)d_in[0];
    const float* src = (const float*)d_in[1];
    const float* Wq  = (const float*)d_in[2];
    const float* bq  = (const float*)d_in[3];
    const float* Wk  = (const float*)d_in[4];
    const float* bk  = (const float*)d_in[5];
    const float* Wo  = (const float*)d_in[6];
    const float* bo  = (const float*)d_in[7];
    float* out = (float*)d_out;

    // workspace layout (bytes, all 256-aligned)
    char* ws = (char*)d_ws;
    size_t off = 0;
    float*          Kbuf = (float*)(ws + off);          off += (size_t)S_ * D_ * 4;
    float*          tmps = (float*)(ws + off);          off += (size_t)B_ * H_ * S_ * 4;
    int*            idxs = (int*)(ws + off);            off += (size_t)B_ * H_ * TOPK_ * 4;
    off = (off + 255) & ~(size_t)255;
    float*          tok  = (float*)(ws + off);          off += (size_t)B_ * TOPK_ * D_ * 4;
    unsigned short* Kh   = (unsigned short*)(ws + off); off += (size_t)1024 * D_ * 2;
    unsigned short* Kl   = (unsigned short*)(ws + off); off += (size_t)1024 * D_ * 2;
    unsigned short* WqTh = (unsigned short*)(ws + off); off += (size_t)D_ * D_ * 2;
    unsigned short* WqTl = (unsigned short*)(ws + off); off += (size_t)D_ * D_ * 2;
    unsigned short* WkTh = (unsigned short*)(ws + off); off += (size_t)D_ * D_ * 2;
    unsigned short* WkTl = (unsigned short*)(ws + off); off += (size_t)D_ * D_ * 2;
    unsigned short* Sh   = (unsigned short*)(ws + off); off += (size_t)1024 * D_ * 2;
    unsigned short* Sl   = (unsigned short*)(ws + off); off += (size_t)1024 * D_ * 2;
    unsigned short* qhb  = (unsigned short*)(ws + off);
    const size_t fixed_bytes = off;
    const size_t q_plane_b = (size_t)L_ * D_ * 2;   // one bf16 plane per batch

    int nb_fit = 1;
    if (ws_size > fixed_bytes) {
        size_t f = (ws_size - fixed_bytes) / (2 * q_plane_b);
        nb_fit = (f < 1) ? 1 : (f > 8 ? 8 : (int)f);
    }

    hipMemsetAsync(tmps, 0, (size_t)B_ * H_ * S_ * sizeof(float), stream);

    split_src_kernel<<<(1024 * D_) / (256 * 4), 256, 0, stream>>>(src, Sh, Sl);
    {
        dim3 g(D_ / 64, D_ / 64);
        splitWT_kernel<<<g, 256, 0, stream>>>(Wq, WqTh, WqTl);
        splitWT_kernel<<<g, 256, 0, stream>>>(Wk, WkTh, WkTl);
    }

    // K = src @ Wk + bk via 3-term MFMA (writes Kbuf f32 + Kh/Kl bf16)
    kproj_kernel<<<64, 256, 0, stream>>>(Sh, Sl, WkTh, WkTl, bk, Kbuf, Kh, Kl);

    for (int b0 = 0; b0 < B_; b0 += nb_fit) {
        int nb = (B_ - b0 < nb_fit) ? (B_ - b0) : nb_fit;
        unsigned short* qlb = qhb + (size_t)nb_fit * q_plane_b / 2;
        qproj_kernel<<<nb * 128, 256, 0, stream>>>(
            tgt + (size_t)b0 * L_ * D_, WqTh, WqTl, bq, qhb, qlb);
        scores2p_kernel<<<nb * 128, 256, 0, stream>>>(qhb, qlb, Kh, Kl, tmps, b0);
    }

    topk_kernel<<<B_ * H_, 256, 0, stream>>>(tmps, idxs);
    gather_kernel<<<(B_ * TOPK_ * D_ + 255) / 256, 256, 0, stream>>>(Kbuf, idxs, tok);
    {
        dim3 g(D_ / 64, (B_ * TOPK_ + 63) / 64);
        gemm_bias_kernel<<<g, 256, 0, stream>>>(tok, Wo, bo, out, B_ * TOPK_, D_, D_);
    }
}